// Round 6
// baseline (325.422 us; speedup 1.0000x reference)
//
#include <hip/hip_runtime.h>
#include <math.h>

// Problem constants: B=8, C=32, F=32, K=3, H=W=32
#define NB 8
#define NC 32
#define NF 32
#define NH 32
#define NW 32
#define NQ 9
#define PROWS 34
#define PCOLS 36            // padded cols (+2 slack, rows 16B-aligned)

// coeff records: one per (q,c,f), 32 halves (64 B):
//   [a0..a5,0,0 | 0,d0,d1,d2,d3,0,0,0 | zero8 | zero8]
#define NREC (NQ * NC * NF)                    // 9216
#define CFH_BYTES (NREC * 64)                  // 589824
#define XPAD_FLOATS (NB * NC * PROWS * PCOLS)  // 313344

typedef _Float16 h8  __attribute__((ext_vector_type(8)));
typedef float    f16v __attribute__((ext_vector_type(16)));

// --- prep 1: pack coeffs into f16 MFMA-ready B-fragment records --------------
__global__ __launch_bounds__(256) void pack_coeffs(
    const float* __restrict__ nums, const float* __restrict__ dens,
    _Float16* __restrict__ cfh)
{
    int r = blockIdx.x * 256 + threadIdx.x;
    if (r >= NREC) return;
    int q = r >> 10, c = (r >> 5) & 31, f = r & 31;   // r = (q*32+c)*32+f
    int src = (f * NQ + q) * NC + c;                  // a[f,q,c], b[f,q,c]
    const float* a = nums + (size_t)src * 6;
    const float* d = dens + (size_t)src * 4;
    _Float16* o = cfh + (size_t)r * 32;
#pragma unroll
    for (int i = 0; i < 32; ++i) o[i] = (_Float16)0.f;
    o[0] = (_Float16)a[0]; o[1] = (_Float16)a[1]; o[2] = (_Float16)a[2];
    o[3] = (_Float16)a[3]; o[4] = (_Float16)a[4]; o[5] = (_Float16)a[5];
    // den = 1 + |sum_p d_p * w^(p+1)|  -> k-slots 1..4
    o[9] = (_Float16)d[0]; o[10] = (_Float16)d[1];
    o[11] = (_Float16)d[2]; o[12] = (_Float16)d[3];
}

// --- prep 2: zero-padded copy of x ------------------------------------------
__global__ __launch_bounds__(256) void prepad_x(
    const float* __restrict__ x, float* __restrict__ xp)
{
    int idx = blockIdx.x * 256 + threadIdx.x; // < XPAD_FLOATS exactly
    int px  = idx % PCOLS;
    int t1  = idx / PCOLS;
    int py  = t1 % PROWS;
    int bc  = t1 / PROWS;
    float v = 0.f;
    if (py >= 1 && py <= NH && px >= 1 && px <= NW)
        v = x[(size_t)bc * NH * NW + (py - 1) * NW + (px - 1)];
    xp[idx] = v;
}

// --- main MFMA kernel --------------------------------------------------------
// Wave = one image row (M=32 pixels) x all f (N=32) x 2 channels; per (c,q):
// A[m][k] = w_m^k (k=0..5, f16), B_num[k][f]=a_k, B_den[k]=d at k=1..4.
// D_num, D_den via v_mfma_f32_32x32x16_f16; epilogue acc += num*rcp(1+|den|).
// Block = 4 waves (8 channels); 4 blocks per row-tile cover C=32; grid=1024
// (4 blocks/CU, 16 waves/CU). LDS cross-wave reduce, then 1M fp32 atomics.
// A/B k-mapping errors cancel (same (group,slot)->k map both operands);
// C/D layout is the HW-verified col=lane&31, row=(r&3)+8*(r>>2)+4*(lane>>5).
__global__ __launch_bounds__(256, 4) void ka_mfma(
    const _Float16* __restrict__ cfh,  // [NQ][NC][NF][32h]
    const float* __restrict__ xpad,    // [B][C][34][36]
    float* __restrict__ out)           // [B][F][32][32] (pre-zeroed)
{
    __shared__ float red[4][NF * 33];  // +1 pad: bank-conflict-free both phases

    const int tid  = threadIdx.x;
    const int wvid = tid >> 6;
    const int lane = tid & 63;
    const int m    = lane & 31;        // A: pixel col; B/D: f
    const int gi   = lane >> 5;        // k-group (0: k=0..7, 1: k=8..15)
    const int bid  = blockIdx.x;       // 0..1023
    const int cg   = bid & 3;
    const int tile = bid >> 2;         // 0..255 = b*32 + y
    const int y    = tile & 31;
    const int bb   = tile >> 5;
    const int c0   = cg * 8 + wvid * 2;

    const float* wb  = xpad + ((size_t)(bb * NC + c0) * PROWS + y) * PCOLS + m;
    const h8* rec0   = (const h8*)cfh;          // 4 h8 per record

    const h8 az = {0, 0, 0, 0, 0, 0, 0, 0};
    const f16v zc = {0.f, 0.f, 0.f, 0.f, 0.f, 0.f, 0.f, 0.f,
                     0.f, 0.f, 0.f, 0.f, 0.f, 0.f, 0.f, 0.f};
    f16v acc = zc;

#pragma unroll
    for (int ci = 0; ci < 2; ++ci) {
        const int c = c0 + ci;
        const float* wc = wb + (size_t)ci * PROWS * PCOLS;
        // 9 window values for this pixel: rows y..y+2, cols m..m+2 (padded)
        float wvv[9];
#pragma unroll
        for (int r = 0; r < 3; ++r)
#pragma unroll
            for (int cc = 0; cc < 3; ++cc)
                wvv[r * 3 + cc] = wc[r * PCOLS + cc];

#pragma unroll
        for (int q = 0; q < NQ; ++q) {
            const float w = wvv[q];
            h8 A = az;
            if (gi == 0) {
                const float w2 = w * w, w3 = w2 * w, w4 = w2 * w2, w5 = w4 * w;
                A[0] = (_Float16)1.f; A[1] = (_Float16)w;  A[2] = (_Float16)w2;
                A[3] = (_Float16)w3;  A[4] = (_Float16)w4; A[5] = (_Float16)w5;
            }
            // B fragments: lane f=m; g0 -> real coeffs, g1 -> zero8 rows
            const h8* rec = rec0 + ((size_t)((q * NC + c) * NF + m)) * 4;
            const h8 Bn = rec[2 * gi];     // g0: num8,  g1: zero8
            const h8 Bd = rec[1 + gi];     // g0: den8,  g1: zero8

            const f16v dn = __builtin_amdgcn_mfma_f32_32x32x16_f16(A, Bn, zc, 0, 0, 0);
            const f16v dd = __builtin_amdgcn_mfma_f32_32x32x16_f16(A, Bd, zc, 0, 0, 0);

#pragma unroll
            for (int r = 0; r < 16; ++r) {
                const float de = 1.f + fabsf(dd[r]);
                acc[r] = fmaf(dn[r], __builtin_amdgcn_rcpf(de), acc[r]);
            }
        }
    }

    // cross-wave reduction: D layout -> red[wave][f*33 + pixel]
#pragma unroll
    for (int r = 0; r < 16; ++r) {
        const int mr = (r & 3) + 8 * (r >> 2) + 4 * gi;  // pixel row index
        red[wvid][m * 33 + mr] = acc[r];                 // m here = f (D col)
    }
    __syncthreads();

#pragma unroll
    for (int j = 0; j < 4; ++j) {
        const int ff = (tid >> 5) + j * 8;
        const int mm = tid & 31;
        const int li = ff * 33 + mm;
        const float s = red[0][li] + red[1][li] + red[2][li] + red[3][li];
        unsafeAtomicAdd(out + ((size_t)(bb * NF + ff) * NH + y) * NW + mm, s);
    }
}

extern "C" void kernel_launch(void* const* d_in, const int* in_sizes, int n_in,
                              void* d_out, int out_size, void* d_ws, size_t ws_size,
                              hipStream_t stream) {
    const float* x    = (const float*)d_in[0];
    const float* nums = (const float*)d_in[1];
    const float* dens = (const float*)d_in[2];
    float* out = (float*)d_out;

    _Float16* cfh = (_Float16*)d_ws;                       // 589824 B
    float* xpad   = (float*)((char*)d_ws + CFH_BYTES);     // 1253376 B

    pack_coeffs<<<(NREC + 255) / 256, 256, 0, stream>>>(nums, dens, cfh);
    prepad_x<<<XPAD_FLOATS / 256, 256, 0, stream>>>(x, xpad);

    // atomic accumulation target must start at zero (harness poisons d_out)
    hipMemsetAsync(d_out, 0, (size_t)out_size * sizeof(float), stream);

    dim3 grid(NB * NH * 4); // 1024 blocks: (b, row, c-group)
    ka_mfma<<<grid, 256, 0, stream>>>(cfh, xpad, out);
}

// Round 7
// 281.346 us; speedup vs baseline: 1.1567x; 1.1567x over previous
//
#include <hip/hip_runtime.h>
#include <math.h>

// Problem constants: B=8, C=32, F=32, K=3, H=W=32
#define NB 8
#define NC 32
#define NF 32
#define NH 32
#define NW 32
#define NQ 9
#define PROWS 34
#define PCOLS 36            // padded cols (+2 slack, rows 16B-aligned)

// coeff records: one per (q,c,f), 32 halves (64 B):
//   h8[0] = [a0..a5, 0, 0]            (num coeffs, k=0..7)
//   h8[1] = [0, d0, d1, d2, d3, 0,0,0] (den coeffs, SAME k-space: den=Σ d_p w^{p+1})
//   h8[2] = h8[3] = zeros              (loaded by quads 1..3)
#define NREC (NQ * NC * NF)                    // 9216
#define CFH_BYTES (NREC * 64)                  // 589824
#define XPAD_FLOATS (NB * NC * PROWS * PCOLS)  // 313344

typedef _Float16 h8 __attribute__((ext_vector_type(8)));
typedef float f32x4 __attribute__((ext_vector_type(4)));
typedef float f4 __attribute__((ext_vector_type(4), aligned(4)));

// --- prep 1: pack coeffs, record r = (q*NC + c)*NF + f -----------------------
__global__ __launch_bounds__(256) void pack_coeffs(
    const float* __restrict__ nums, const float* __restrict__ dens,
    _Float16* __restrict__ cfh)
{
    int r = blockIdx.x * 256 + threadIdx.x;
    if (r >= NREC) return;
    int q = r >> 10, c = (r >> 5) & 31, f = r & 31;
    int src = (f * NQ + q) * NC + c;
    const float* a = nums + (size_t)src * 6;
    const float* d = dens + (size_t)src * 4;
    _Float16* o = cfh + (size_t)r * 32;
#pragma unroll
    for (int i = 0; i < 32; ++i) o[i] = (_Float16)0.f;
    o[0] = (_Float16)a[0]; o[1] = (_Float16)a[1]; o[2] = (_Float16)a[2];
    o[3] = (_Float16)a[3]; o[4] = (_Float16)a[4]; o[5] = (_Float16)a[5];
    o[9] = (_Float16)d[0]; o[10] = (_Float16)d[1];
    o[11] = (_Float16)d[2]; o[12] = (_Float16)d[3];
}

// --- prep 2: zero-padded copy of x ------------------------------------------
__global__ __launch_bounds__(256) void prepad_x(
    const float* __restrict__ x, float* __restrict__ xp)
{
    int idx = blockIdx.x * 256 + threadIdx.x;
    int px  = idx % PCOLS;
    int t1  = idx / PCOLS;
    int py  = t1 % PROWS;
    int bc  = t1 / PROWS;
    float v = 0.f;
    if (py >= 1 && py <= NH && px >= 1 && px <= NW)
        v = x[(size_t)bc * NH * NW + (py - 1) * NW + (px - 1)];
    xp[idx] = v;
}

// --- main MFMA kernel (16x16x32 f16: C/D = 4 regs, spill-proof) -------------
// Wave: M=16 pixels (half image row) x N=32 f (2 tiles) x 2 channels x 9 q.
// Per (q,c): A[m][k]=w_m^k (k=0..5, quad-0 lanes only), Bn[k][f]=a_k,
// Bd[k][f]=d_{k-1} (k=1..4). 4 MFMAs + 8-element epilogue.
// Block = 4 waves (8 channels), grid = 512 px-tiles x 4 c-groups = 2048.
// LDS reduce over the 4 waves -> coalesced fp32 atomics.
__global__ __launch_bounds__(256, 6) void ka_mfma(
    const _Float16* __restrict__ cfh,  // [NQ][NC][NF] 64B records
    const float* __restrict__ xpad,    // [B][C][34][36]
    float* __restrict__ out)           // [B][F][32][32] (pre-zeroed)
{
    __shared__ float red[4][NF * 17];  // [wave][f*17 + px], px-dim padded

    const int tid  = threadIdx.x;
    const int wvid = tid >> 6;
    const int lane = tid & 63;
    const int l15  = lane & 15;        // A: pixel m; B/D: f (low 4 bits)
    const int quad = lane >> 4;        // k-group: quad 0 holds k=0..7
    const int bid  = blockIdx.x;       // 0..2047
    const int cg   = bid & 3;
    const int tile = bid >> 2;         // 0..511 = (b*32 + y)*2 + xh
    const int xh   = tile & 1;
    const int y    = (tile >> 1) & 31;
    const int bb   = tile >> 6;
    const int c0   = cg * 8 + wvid * 2;
    const int x    = xh * 16 + l15;    // this lane's pixel column

    // per-lane record sub-offsets: quad 0 reads real fragments, others zero16
    const int offn = (quad == 0) ? 0  : 32;
    const int offd = (quad == 0) ? 16 : 32;

    const h8 az = {0, 0, 0, 0, 0, 0, 0, 0};
    const f32x4 z4 = {0.f, 0.f, 0.f, 0.f};
    f32x4 acc0 = z4, acc1 = z4;        // f-tiles 0 (f=0..15) and 1 (f=16..31)

#pragma unroll
    for (int ci = 0; ci < 2; ++ci) {
        const int c = c0 + ci;
        const float* wbase = xpad + ((size_t)(bb * NC + c) * PROWS + y) * PCOLS + x;
        f4 win[3];
#pragma unroll
        for (int r = 0; r < 3; ++r)
            win[r] = *(const f4*)(wbase + r * PCOLS);

        const char* recc = (const char*)cfh + ((size_t)c * NF + l15) * 64;

#pragma unroll
        for (int q = 0; q < NQ; ++q) {
            const int qi = q / 3, qj = q - qi * 3;
            const float w = win[qi][qj];

            // A fragment: powers w^0..w^5 in quad 0, zeros elsewhere
            h8 A = az;
            if (quad == 0) {
                const float w2 = w * w, w3 = w2 * w, w4 = w2 * w2, w5 = w4 * w;
                A[0] = (_Float16)1.f; A[1] = (_Float16)w;  A[2] = (_Float16)w2;
                A[3] = (_Float16)w3;  A[4] = (_Float16)w4; A[5] = (_Float16)w5;
            }

            const char* rb = recc + (size_t)q * (NC * NF * 64);
            const h8 Bn0 = *(const h8*)(rb + offn);
            const h8 Bd0 = *(const h8*)(rb + offd);
            const h8 Bn1 = *(const h8*)(rb + 16 * 64 + offn);
            const h8 Bd1 = *(const h8*)(rb + 16 * 64 + offd);

            {
                const f32x4 dn = __builtin_amdgcn_mfma_f32_16x16x32_f16(A, Bn0, z4, 0, 0, 0);
                const f32x4 dd = __builtin_amdgcn_mfma_f32_16x16x32_f16(A, Bd0, z4, 0, 0, 0);
#pragma unroll
                for (int r = 0; r < 4; ++r) {
                    const float de = 1.f + fabsf(dd[r]);
                    acc0[r] = fmaf(dn[r], __builtin_amdgcn_rcpf(de), acc0[r]);
                }
            }
            {
                const f32x4 dn = __builtin_amdgcn_mfma_f32_16x16x32_f16(A, Bn1, z4, 0, 0, 0);
                const f32x4 dd = __builtin_amdgcn_mfma_f32_16x16x32_f16(A, Bd1, z4, 0, 0, 0);
#pragma unroll
                for (int r = 0; r < 4; ++r) {
                    const float de = 1.f + fabsf(dd[r]);
                    acc1[r] = fmaf(dn[r], __builtin_amdgcn_rcpf(de), acc1[r]);
                }
            }
        }
    }

    // D layout: col = lane&15 = f_local, row = quad*4 + reg = pixel.
    // Stage to LDS, reduce the block's 4 waves, emit coalesced atomics.
#pragma unroll
    for (int r = 0; r < 4; ++r) {
        red[wvid][l15 * 17 + quad * 4 + r]        = acc0[r];
        red[wvid][(16 + l15) * 17 + quad * 4 + r] = acc1[r];
    }
    __syncthreads();

    {
        const int ff = tid >> 3;          // 0..31
        const int p0 = (tid & 7) * 2;     // 0,2,..,14
        const int li = ff * 17 + p0;
        const float s0 = red[0][li] + red[1][li] + red[2][li] + red[3][li];
        const float s1 = red[0][li + 1] + red[1][li + 1] + red[2][li + 1] + red[3][li + 1];
        float* op = out + ((size_t)(bb * NF + ff) * NH + y) * NW + xh * 16 + p0;
        unsafeAtomicAdd(op,     s0);
        unsafeAtomicAdd(op + 1, s1);
    }
}

extern "C" void kernel_launch(void* const* d_in, const int* in_sizes, int n_in,
                              void* d_out, int out_size, void* d_ws, size_t ws_size,
                              hipStream_t stream) {
    const float* x    = (const float*)d_in[0];
    const float* nums = (const float*)d_in[1];
    const float* dens = (const float*)d_in[2];
    float* out = (float*)d_out;

    _Float16* cfh = (_Float16*)d_ws;                       // 589824 B
    float* xpad   = (float*)((char*)d_ws + CFH_BYTES);     // 1253376 B

    pack_coeffs<<<(NREC + 255) / 256, 256, 0, stream>>>(nums, dens, cfh);
    prepad_x<<<XPAD_FLOATS / 256, 256, 0, stream>>>(x, xpad);

    // atomic accumulation target must start at zero (harness poisons d_out)
    hipMemsetAsync(d_out, 0, (size_t)out_size * sizeof(float), stream);

    dim3 grid(NB * NH * 2 * 4); // 2048: (b, y, xhalf) x c-group
    ka_mfma<<<grid, 256, 0, stream>>>(cfh, xpad, out);
}